// Round 1
// baseline (2153.545 us; speedup 1.0000x reference)
//
#include <hip/hip_runtime.h>

#define BN_S 0.9999950000374997f

typedef __attribute__((ext_vector_type(8))) short bf16x8;
typedef __attribute__((ext_vector_type(4))) float f32x4;

__device__ inline short f2bf(float f) {
    union { float f; unsigned u; } v; v.f = f;
    return (short)((v.u + 0x7FFFu + ((v.u >> 16) & 1u)) >> 16);
}

// ---------------- gates: top-k mask + masked softmax -> p[14][32][8] ----------
__global__ void gates_k(const float* __restrict__ g, const int* __restrict__ topp,
                        float* __restrict__ p)
{
    int t = blockIdx.x * blockDim.x + threadIdx.x;
    if (t >= 14 * 32) return;
    int top = topp[0];
    float v[8]; bool sel[8];
    for (int o = 0; o < 8; ++o) { v[o] = g[t * 8 + o]; sel[o] = false; }
    for (int it = 0; it < top; ++it) {
        int bi = 0; float bv = -3.4e38f;
        for (int o = 0; o < 8; ++o)
            if (!sel[o] && v[o] > bv) { bv = v[o]; bi = o; }
        sel[bi] = true;
    }
    float mx = -3.4e38f;
    for (int o = 0; o < 8; ++o) if (sel[o]) mx = fmaxf(mx, v[o]);
    float e[8]; float sum = 0.0f;
    for (int o = 0; o < 8; ++o) { e[o] = sel[o] ? expf(v[o] - mx) : 0.0f; sum += e[o]; }
    for (int o = 0; o < 8; ++o) p[t * 8 + o] = e[o] / sum;
}

// ---------------- zero d_out ------------------------------------------------
__global__ void zero_k(float4* __restrict__ p, int n) {
    int i = blockIdx.x * blockDim.x + threadIdx.x;
    if (i < n) p[i] = make_float4(0.f, 0.f, 0.f, 0.f);
}

// ---------------- 1x1 conv as MFMA GEMM: out[b,co,n] (+)= scale * W@X --------
// W: [128][K] row-major f32.  X: in + b*in_bs, [K][1024] (channel stride 1024).
// gw: per-sample gate ptr (stride 8) or null. If gw[b]==0 -> whole block exits.
// ACC: out[idx] += BN*gw[b]*acc ; else out[idx] = BN*acc.
template<int K, bool RELU, bool ACC>
__global__ void __launch_bounds__(256)
conv1x1_k(const float* __restrict__ in, long in_bs,
          const float* __restrict__ w,
          float* __restrict__ out, long out_bs,
          const float* __restrict__ gw)
{
    const int b = blockIdx.z;
    float scale = BN_S;
    if (gw) {
        float g = gw[(long)b * 8];
        if (g == 0.0f) return;
        if (ACC) scale *= g;
    }
    const int tid = threadIdx.x;
    const int wave = tid >> 6, lane = tid & 63;
    const int quad = lane >> 4, l16 = lane & 15;
    const int co0 = blockIdx.y * 32 + (wave & 1) * 16;
    const int n0  = blockIdx.x * 128 + (wave >> 1) * 64;
    const float* __restrict__ xb = in + (long)b * in_bs;

    f32x4 acc[4] = {{0,0,0,0},{0,0,0,0},{0,0,0,0},{0,0,0,0}};
    for (int k0 = 0; k0 < K; k0 += 32) {
        const float* wr = w + (long)(co0 + l16) * K + k0 + quad * 8;
        bf16x8 af;
#pragma unroll
        for (int j = 0; j < 8; ++j) af[j] = f2bf(wr[j]);
        const float* xc = xb + (long)(k0 + quad * 8) * 1024 + n0 + l16;
#pragma unroll
        for (int s = 0; s < 4; ++s) {
            bf16x8 bfv;
#pragma unroll
            for (int j = 0; j < 8; ++j) {
                float v = xc[(long)j * 1024 + s * 16];
                if (RELU) v = fmaxf(v, 0.0f);
                bfv[j] = f2bf(v);
            }
            acc[s] = __builtin_amdgcn_mfma_f32_16x16x32_bf16(af, bfv, acc[s], 0, 0, 0);
        }
    }
#pragma unroll
    for (int s = 0; s < 4; ++s)
#pragma unroll
        for (int r = 0; r < 4; ++r) {
            long idx = (long)b * out_bs + (long)(co0 + quad * 4 + r) * 1024
                     + n0 + s * 16 + l16;
            float v = acc[s][r] * scale;
            if (ACC) out[idx] += v; else out[idx] = v;
        }
}

// ---------------- depthwise conv (relu on input), out contiguous [B][128][1024]
__global__ void __launch_bounds__(256)
dwconv_k(const float* __restrict__ in, long in_bs,
         const float* __restrict__ wd, int ksz, int dil, int pad,
         float* __restrict__ out, const float* __restrict__ gw)
{
    const int c = blockIdx.x, b = blockIdx.y;
    if (gw && gw[(long)b * 8] == 0.0f) return;
    __shared__ float t[1024];
    __shared__ float wl[25];
    const float* src = in + (long)b * in_bs + (long)c * 1024;
    for (int i = threadIdx.x; i < 1024; i += 256) t[i] = fmaxf(src[i], 0.0f);
    if (threadIdx.x < ksz * ksz) wl[threadIdx.x] = wd[(long)c * ksz * ksz + threadIdx.x];
    __syncthreads();
    float* dst = out + ((long)b * 128 + c) * 1024;
    for (int i = threadIdx.x; i < 1024; i += 256) {
        int h = i >> 5, w = i & 31;
        float s = 0.0f;
        for (int ki = 0; ki < ksz; ++ki) {
            int y = h - pad + ki * dil;
            if ((unsigned)y < 32u) {
                for (int kj = 0; kj < ksz; ++kj) {
                    int x = w - pad + kj * dil;
                    if ((unsigned)x < 32u) s += wl[ki * ksz + kj] * t[(y << 5) + x];
                }
            }
        }
        dst[i] = s;
    }
}

// ---------------- pools + skip, accumulate into state ------------------------
__global__ void __launch_bounds__(256)
pool_skip_k(const float* __restrict__ in, long in_bs,
            float* __restrict__ out, long out_bs,
            const float* __restrict__ gw)
{
    const int c = blockIdx.x, b = blockIdx.y;
    float w1 = gw[(long)b * 8 + 1], w2 = gw[(long)b * 8 + 2], w3 = gw[(long)b * 8 + 3];
    if (w1 == 0.0f && w2 == 0.0f && w3 == 0.0f) return;
    w1 *= BN_S; w2 *= BN_S;
    __shared__ float t[1024];
    const float* src = in + (long)b * in_bs + (long)c * 1024;
    for (int i = threadIdx.x; i < 1024; i += 256) t[i] = src[i];
    __syncthreads();
    float* dst = out + (long)b * out_bs + (long)c * 1024;
    for (int i = threadIdx.x; i < 1024; i += 256) {
        int h = i >> 5, w = i & 31;
        int y0 = max(h - 1, 0), y1 = min(h + 1, 31);
        int x0 = max(w - 1, 0), x1 = min(w + 1, 31);
        float mx = -3.4e38f, sm = 0.0f;
        for (int y = y0; y <= y1; ++y)
            for (int x = x0; x <= x1; ++x) {
                float v = t[(y << 5) + x];
                mx = fmaxf(mx, v); sm += v;
            }
        float cnt = (float)((y1 - y0 + 1) * (x1 - x0 + 1));
        dst[i] += w1 * mx + w2 * (sm / cnt) + w3 * t[i];
    }
}

extern "C" void kernel_launch(void* const* d_in, const int* in_sizes, int n_in,
                              void* d_out, int out_size, void* d_ws, size_t ws_size,
                              hipStream_t stream)
{
    const float* s0   = (const float*)d_in[0];
    const float* s1   = (const float*)d_in[1];
    const float* gts  = (const float*)d_in[2];
    const float* pre0 = (const float*)d_in[3];
    const float* pre1 = (const float*)d_in[4];
    const float* s3d1 = (const float*)d_in[5];
    const float* s3p1 = (const float*)d_in[6];
    const float* s3d2 = (const float*)d_in[7];
    const float* s3p2 = (const float*)d_in[8];
    const float* s5d1 = (const float*)d_in[9];
    const float* s5p1 = (const float*)d_in[10];
    const float* s5d2 = (const float*)d_in[11];
    const float* s5p2 = (const float*)d_in[12];
    const float* d3d  = (const float*)d_in[13];
    const float* d3p  = (const float*)d_in[14];
    const float* d5d  = (const float*)d_in[15];
    const float* d5p  = (const float*)d_in[16];
    const int*   topp = (const int*)d_in[17];
    float* out = (float*)d_out;

    float* ws  = (float*)d_ws;
    float* p   = ws;                       // 14*32*8 floats
    float* s0p = ws + 4096;                // [32][128][1024]
    float* s1p = s0p + 4194304;
    float* t0  = s1p + 4194304;
    float* t1  = t0 + 4194304;

    zero_k<<<4194304 / 256, 256, 0, stream>>>((float4*)d_out, 4194304);
    gates_k<<<2, 256, 0, stream>>>(gts, topp, p);

    dim3 cgrid(8, 4, 32);   // n-tiles, co-tiles, batch
    dim3 pgrid(128, 32);    // channel, batch
    const long SB = 128 * 1024L, OB = 512 * 1024L;

    conv1x1_k<512, true, false><<<cgrid, 256, 0, stream>>>(s0, OB, pre0, s0p, SB, nullptr);
    conv1x1_k<512, true, false><<<cgrid, 256, 0, stream>>>(s1, OB, pre1, s1p, SB, nullptr);

    const float* stp[6]; long sbs[6];
    stp[0] = s0p; sbs[0] = SB;
    stp[1] = s1p; sbs[1] = SB;

    int offset = 0;
    for (int i = 0; i < 4; ++i) {
        float* so = out + (long)i * 128 * 1024;   // channel offset into concat output
        int cnt = 2 + i;
        for (int j = 0; j < cnt; ++j) {
            int m = offset + j;
            const float* x = stp[j]; long xbs = sbs[j];
            const float* pm = p + (long)m * 256;
            // sep_conv_3x3 (op 4)
            dwconv_k<<<pgrid, 256, 0, stream>>>(x, xbs, s3d1 + (long)m * 1152, 3, 1, 1, t0, pm + 4);
            conv1x1_k<128, false, false><<<cgrid, 256, 0, stream>>>(t0, SB, s3p1 + (long)m * 16384, t1, SB, pm + 4);
            dwconv_k<<<pgrid, 256, 0, stream>>>(t1, SB, s3d2 + (long)m * 1152, 3, 1, 1, t0, pm + 4);
            conv1x1_k<128, false, true><<<cgrid, 256, 0, stream>>>(t0, SB, s3p2 + (long)m * 16384, so, OB, pm + 4);
            // sep_conv_5x5 (op 5)
            dwconv_k<<<pgrid, 256, 0, stream>>>(x, xbs, s5d1 + (long)m * 3200, 5, 1, 2, t0, pm + 5);
            conv1x1_k<128, false, false><<<cgrid, 256, 0, stream>>>(t0, SB, s5p1 + (long)m * 16384, t1, SB, pm + 5);
            dwconv_k<<<pgrid, 256, 0, stream>>>(t1, SB, s5d2 + (long)m * 3200, 5, 1, 2, t0, pm + 5);
            conv1x1_k<128, false, true><<<cgrid, 256, 0, stream>>>(t0, SB, s5p2 + (long)m * 16384, so, OB, pm + 5);
            // dil_conv_3x3 (op 6): k=3, dil=2, pad=2
            dwconv_k<<<pgrid, 256, 0, stream>>>(x, xbs, d3d + (long)m * 1152, 3, 2, 2, t0, pm + 6);
            conv1x1_k<128, false, true><<<cgrid, 256, 0, stream>>>(t0, SB, d3p + (long)m * 16384, so, OB, pm + 6);
            // dil_conv_5x5 (op 7): k=5, dil=2, pad=4
            dwconv_k<<<pgrid, 256, 0, stream>>>(x, xbs, d5d + (long)m * 3200, 5, 2, 4, t0, pm + 7);
            conv1x1_k<128, false, true><<<cgrid, 256, 0, stream>>>(t0, SB, d5p + (long)m * 16384, so, OB, pm + 7);
            // max/avg pool + skip (ops 1,2,3)
            pool_skip_k<<<pgrid, 256, 0, stream>>>(x, xbs, so, OB, pm);
        }
        stp[2 + i] = so; sbs[2 + i] = OB;
        offset += cnt;
    }
}